// Round 4
// baseline (417.711 us; speedup 1.0000x reference)
//
#include <hip/hip_runtime.h>

// out[n, k*D + d] = M[k, n, d]  with K=4, N=500000, D=128, fp32.
// Wave-per-row mapping: wave w owns output row n.
//   lane l:  k0 = l>>5 (0/1), c = l&31 (float4 column)
//   load j=0: planes {0,1}, j=1: planes {2,3} -> 2x512B segments per instr
//   store: out4[n*128 + 64j + l] -> fully lane-consecutive (1KB/instr)
// Regular (cached) loads; non-temporal stores only. 2x manual unroll:
// 4 loads in flight before the first store.

typedef float v4f __attribute__((ext_vector_type(4)));

static constexpr long long N = 500000;
static constexpr long long ROW4   = 128 / 4;        // 32 v4f per (k,n) row
static constexpr long long PLANE4 = N * ROW4;       // v4f per k-plane

__global__ void msgcat_kernel(const v4f* __restrict__ in, v4f* __restrict__ out) {
    const int lane        = threadIdx.x & 63;
    const int waveInBlock = threadIdx.x >> 6;
    const int wavesPerBlk = blockDim.x >> 6;
    const long long totalWaves = (long long)gridDim.x * wavesPerBlk;

    const int k0 = lane >> 5;        // 0 or 1
    const int c  = lane & 31;        // v4f column within 128-float row

    const long long pA = (long long)k0 * PLANE4 + c;        // planes 0/1
    const long long pB = (long long)(k0 + 2) * PLANE4 + c;  // planes 2/3

    long long n = (long long)blockIdx.x * wavesPerBlk + waveInBlock;
    for (; n + totalWaves < N; n += 2 * totalWaves) {
        const long long n1 = n + totalWaves;
        const long long i0 = n  * ROW4, i1 = n1 * ROW4;
        // issue 4 independent loads
        v4f a0 = in[pA + i0];
        v4f b0 = in[pB + i0];
        v4f a1 = in[pA + i1];
        v4f b1 = in[pB + i1];
        const long long o0 = n  * (4 * ROW4) + lane;
        const long long o1 = n1 * (4 * ROW4) + lane;
        __builtin_nontemporal_store(a0, &out[o0]);
        __builtin_nontemporal_store(b0, &out[o0 + 64]);
        __builtin_nontemporal_store(a1, &out[o1]);
        __builtin_nontemporal_store(b1, &out[o1 + 64]);
    }
    if (n < N) {
        const long long i0 = n * ROW4;
        v4f a0 = in[pA + i0];
        v4f b0 = in[pB + i0];
        const long long o0 = n * (4 * ROW4) + lane;
        __builtin_nontemporal_store(a0, &out[o0]);
        __builtin_nontemporal_store(b0, &out[o0 + 64]);
    }
}

extern "C" void kernel_launch(void* const* d_in, const int* in_sizes, int n_in,
                              void* d_out, int out_size, void* d_ws, size_t ws_size,
                              hipStream_t stream) {
    const v4f* in  = (const v4f*)d_in[0];
    v4f*       out = (v4f*)d_out;
    const int block = 256;                 // 4 waves/block
    const int grid  = 2048;                // 8 blocks/CU on 256 CUs
    msgcat_kernel<<<grid, block, 0, stream>>>(in, out);
}

// Round 5
// 368.710 us; speedup vs baseline: 1.1329x; 1.1329x over previous
//
#include <hip/hip_runtime.h>

// out[n, k*D + d] = M[k, n, d]  with K=4, N=500000, D=128, fp32.
// Wave w owns ADJACENT output rows 2w and 2w+1.
//   lane l:  k0 = l>>5 (0/1), c = l&31 (float4 column)
//   loads: per plane-half, rows 2w,2w+1 are contiguous -> 1KB dense per
//          plane per pair; 4 independent loads in flight.
//   stores: rows 2w,2w+1 -> 4KB contiguous per wave, 1KB dense per instr.
// Non-temporal on BOTH sides (R3's NT-load win restored).

typedef float v4f __attribute__((ext_vector_type(4)));

static constexpr long long N = 500000;              // even -> pairs exact
static constexpr long long ROW4   = 128 / 4;        // 32 v4f per (k,n) row
static constexpr long long PLANE4 = N * ROW4;       // v4f per k-plane
static constexpr long long NPAIR  = N / 2;          // 250000 row-pairs

__global__ void msgcat_kernel(const v4f* __restrict__ in, v4f* __restrict__ out) {
    const int lane        = threadIdx.x & 63;
    const int waveInBlock = threadIdx.x >> 6;
    const int wavesPerBlk = blockDim.x >> 6;
    const long long totalWaves = (long long)gridDim.x * wavesPerBlk;

    const int k0 = lane >> 5;        // 0 or 1
    const int c  = lane & 31;        // v4f column within 128-float row

    const long long pA = (long long)k0 * PLANE4 + c;        // planes 0/1
    const long long pB = (long long)(k0 + 2) * PLANE4 + c;  // planes 2/3

    for (long long p = (long long)blockIdx.x * wavesPerBlk + waveInBlock;
         p < NPAIR; p += totalWaves) {
        const long long n0 = 2 * p, n1 = n0 + 1;
        const long long i0 = n0 * ROW4, i1 = n1 * ROW4;
        v4f a0 = __builtin_nontemporal_load(&in[pA + i0]);
        v4f a1 = __builtin_nontemporal_load(&in[pA + i1]);
        v4f b0 = __builtin_nontemporal_load(&in[pB + i0]);
        v4f b1 = __builtin_nontemporal_load(&in[pB + i1]);
        const long long o0 = n0 * (4 * ROW4) + lane;
        const long long o1 = n1 * (4 * ROW4) + lane;
        __builtin_nontemporal_store(a0, &out[o0]);
        __builtin_nontemporal_store(b0, &out[o0 + 64]);
        __builtin_nontemporal_store(a1, &out[o1]);
        __builtin_nontemporal_store(b1, &out[o1 + 64]);
    }
}

extern "C" void kernel_launch(void* const* d_in, const int* in_sizes, int n_in,
                              void* d_out, int out_size, void* d_ws, size_t ws_size,
                              hipStream_t stream) {
    const v4f* in  = (const v4f*)d_in[0];
    v4f*       out = (v4f*)d_out;
    const int block = 256;                 // 4 waves/block
    const int grid  = 2048;                // 8 blocks/CU on 256 CUs
    msgcat_kernel<<<grid, block, 0, stream>>>(in, out);
}